// Round 1
// baseline (715.774 us; speedup 1.0000x reference)
//
#include <hip/hip_runtime.h>
#include <hip/hip_bf16.h>

#define DEV __device__ __forceinline__

typedef short bf16x8 __attribute__((ext_vector_type(8)));
typedef float f32x4 __attribute__((ext_vector_type(4)));
typedef unsigned short u16x4 __attribute__((ext_vector_type(4)));

static constexpr int Bsz = 4, Tt = 2048, Cch = 2048, Dd = 128, Ee = 16;
static constexpr int Nn = Bsz * Tt;

DEV unsigned short f2bf(float v) {
    __hip_bfloat16 h = __float2bfloat16(v);
    return __builtin_bit_cast(unsigned short, h);
}

// ---------------- sim_matrix column norms ----------------
__global__ __launch_bounds__(256) void colnorm_kernel(const float* __restrict__ sim,
                                                      float* __restrict__ sninv) {
    int e = threadIdx.x & 15, j = threadIdx.x >> 4;
    float ss = 0.f;
    for (int r = j; r < Cch; r += 16) {
        float v = sim[r * Ee + e];
        ss += v * v;
    }
    __shared__ float red[16][17];
    red[j][e] = ss;
    __syncthreads();
    if (threadIdx.x < 16) {
        float s = 0.f;
        for (int t = 0; t < 16; t++) s += red[t][threadIdx.x];
        sninv[threadIdx.x] = 1.f / fmaxf(sqrtf(s), 1e-12f);
    }
}

// ---------------- gating: routing weights + bf16 cast of x ----------------
__global__ __launch_bounds__(256) void gating_kernel(
    const float* __restrict__ x, const float* __restrict__ sim,
    const float* __restrict__ gates, const float* __restrict__ sninv,
    const int* __restrict__ minex,
    float* __restrict__ rw, unsigned short* __restrict__ xb) {
    int n = blockIdx.x;
    const float* xr = x + (size_t)n * Cch;
    unsigned short* xbr = xb + (size_t)n * Cch;
    float ss = 0.f;
    float d[16];
#pragma unroll
    for (int e = 0; e < 16; e++) d[e] = 0.f;
    for (int c = threadIdx.x; c < Cch; c += 256) {
        float xv = xr[c];
        ss += xv * xv;
        xbr[c] = f2bf(xv);
        const float* srow = sim + (size_t)c * 16;
#pragma unroll
        for (int e = 0; e < 16; e++) d[e] += xv * srow[e];
    }
#pragma unroll
    for (int off = 32; off; off >>= 1) {
        ss += __shfl_down(ss, off);
#pragma unroll
        for (int e = 0; e < 16; e++) d[e] += __shfl_down(d[e], off);
    }
    __shared__ float red[4][17];
    int w = threadIdx.x >> 6, lane = threadIdx.x & 63;
    if (lane == 0) {
        red[w][16] = ss;
        for (int e = 0; e < 16; e++) red[w][e] = d[e];
    }
    __syncthreads();
    if (threadIdx.x == 0) {
        float S = red[0][16] + red[1][16] + red[2][16] + red[3][16];
        float inv = 1.f / fmaxf(sqrtf(S), 1e-12f);
        float logit[16];
        bool on[16];
        int nact = 0;
        for (int e = 0; e < 16; e++) {
            float dot = red[0][e] + red[1][e] + red[2][e] + red[3][e];
            float sg = 1.f / (1.f + __expf(-gates[e]));
            float l = dot * inv * sninv[e] - sg;
            logit[e] = l;
            on[e] = (l > 0.f);
            if (on[e]) nact++;
        }
        if (nact == 0) {
            int k = *minex;
            bool ch[16];
            for (int e = 0; e < 16; e++) ch[e] = false;
            for (int kk = 0; kk < k; kk++) {
                int best = -1;
                for (int e = 0; e < 16; e++)
                    if (!ch[e] && (best < 0 || logit[e] > logit[best])) best = e;
                ch[best] = true;
            }
            for (int e = 0; e < 16; e++) on[e] = ch[e];
        }
        float mx = -1e30f;
        for (int e = 0; e < 16; e++)
            if (on[e]) mx = fmaxf(mx, fmaxf(logit[e], 0.f));
        float p[16];
        float sum = 0.f;
        for (int e = 0; e < 16; e++) {
            p[e] = on[e] ? __expf(fmaxf(logit[e], 0.f) - mx) : 0.f;
            sum += p[e];
        }
        float isum = 1.f / sum;
        for (int e = 0; e < 16; e++) rw[(size_t)n * 16 + e] = p[e] * isum;
    }
}

// ---------------- transposes ----------------
__global__ __launch_bounds__(256) void transpose_f32_bf16(
    const float* __restrict__ src, unsigned short* __restrict__ dst,
    int R, int Ccol, long ss, long ds) {
    __shared__ float tile[32][33];
    src += (size_t)blockIdx.z * ss;
    dst += (size_t)blockIdx.z * ds;
    int bx = blockIdx.x * 32, by = blockIdx.y * 32;
    int tx = threadIdx.x & 31, ty = threadIdx.x >> 5;
#pragma unroll
    for (int i = 0; i < 4; i++)
        tile[ty + i * 8][tx] = src[(size_t)(by + ty + i * 8) * Ccol + bx + tx];
    __syncthreads();
#pragma unroll
    for (int i = 0; i < 4; i++)
        dst[(size_t)(bx + ty + i * 8) * R + by + tx] = f2bf(tile[tx][ty + i * 8]);
}

__global__ __launch_bounds__(256) void transpose_u16(
    const unsigned short* __restrict__ src, unsigned short* __restrict__ dst,
    int R, int Ccol, long ss, long ds) {
    __shared__ unsigned short tile[32][33];
    src += (size_t)blockIdx.z * ss;
    dst += (size_t)blockIdx.z * ds;
    int bx = blockIdx.x * 32, by = blockIdx.y * 32;
    int tx = threadIdx.x & 31, ty = threadIdx.x >> 5;
#pragma unroll
    for (int i = 0; i < 4; i++)
        tile[ty + i * 8][tx] = src[(size_t)(by + ty + i * 8) * Ccol + bx + tx];
    __syncthreads();
#pragma unroll
    for (int i = 0; i < 4; i++)
        dst[(size_t)(bx + ty + i * 8) * R + by + tx] = tile[tx][ty + i * 8];
}

// ---------------- NT GEMM: Out[M,N] = A[M,K] * BT[N,K]^T (bf16 in, f32 out) ----------------
// tile 128x128, BK=32, 4 waves of 64x64, 16x16x32 MFMA
template <int CAUSAL>
__global__ __launch_bounds__(256) void gemm_nt(
    const unsigned short* __restrict__ A, long strideA, int lda,
    const unsigned short* __restrict__ BT, long strideB, int ldb,
    float* __restrict__ Out, long strideO, int ldo,
    int K, float scale) {
    __shared__ alignas(16) unsigned short As[128 * 32];
    __shared__ alignas(16) unsigned short Bs[128 * 32];
    const int bm = blockIdx.x * 128;
    const int bn = blockIdx.y * 128;
    if (CAUSAL && bn > bm + 127) return;  // fully-masked causal tile
    A += (size_t)blockIdx.z * strideA;
    BT += (size_t)blockIdx.z * strideB;
    Out += (size_t)blockIdx.z * strideO;
    const int tid = threadIdx.x;
    const int wave = tid >> 6, lane = tid & 63;
    const int lr = lane & 15, lg = lane >> 4;
    const int wr = (wave >> 1) * 64, wc = (wave & 1) * 64;
    f32x4 acc[4][4] = {};

    for (int k0 = 0; k0 < K; k0 += 32) {
        __syncthreads();  // prior MFMA reads of LDS done
#pragma unroll
        for (int i = 0; i < 2; i++) {
            int t = i * 256 + tid;
            int row = t >> 2;
            int kc = (t & 3) << 3;
            __builtin_amdgcn_global_load_lds(
                (const __attribute__((address_space(1))) void*)(A + (size_t)(bm + row) * lda + k0 + kc),
                (__attribute__((address_space(3))) void*)(As + (i * 4 + wave) * 512),
                16, 0, 0);
        }
#pragma unroll
        for (int i = 0; i < 2; i++) {
            int t = i * 256 + tid;
            int row = t >> 2;
            int kc = (t & 3) << 3;
            __builtin_amdgcn_global_load_lds(
                (const __attribute__((address_space(1))) void*)(BT + (size_t)(bn + row) * ldb + k0 + kc),
                (__attribute__((address_space(3))) void*)(Bs + (i * 4 + wave) * 512),
                16, 0, 0);
        }
        __syncthreads();  // compiler drains vmcnt before barrier
        bf16x8 a[4], b[4];
#pragma unroll
        for (int m = 0; m < 4; m++)
            a[m] = *(const bf16x8*)(As + (wr + m * 16 + lr) * 32 + lg * 8);
#pragma unroll
        for (int n = 0; n < 4; n++)
            b[n] = *(const bf16x8*)(Bs + (wc + n * 16 + lr) * 32 + lg * 8);
#pragma unroll
        for (int m = 0; m < 4; m++)
#pragma unroll
            for (int n = 0; n < 4; n++)
                acc[m][n] = __builtin_amdgcn_mfma_f32_16x16x32_bf16(a[m], b[n], acc[m][n], 0, 0, 0);
    }
#pragma unroll
    for (int m = 0; m < 4; m++) {
#pragma unroll
        for (int n = 0; n < 4; n++) {
#pragma unroll
            for (int r = 0; r < 4; r++) {
                int grow = bm + wr + m * 16 + lg * 4 + r;
                int gcol = bn + wc + n * 16 + lr;
                if (!CAUSAL || gcol <= grow)
                    Out[(size_t)grow * ldo + gcol] = acc[m][n][r] * scale;
            }
        }
    }
}

// ---------------- combine: q[n,d] = sum_e rw[n,e] * P[e,n,d] ----------------
__global__ __launch_bounds__(256) void combine_kernel(
    const float* __restrict__ P, const float* __restrict__ rw,
    unsigned short* __restrict__ outb) {
    int idx = blockIdx.x * 256 + threadIdx.x;  // one thread per 4 d's
    int n = idx >> 5;
    int d4 = (idx & 31) << 2;
    float a0 = 0, a1 = 0, a2 = 0, a3 = 0;
#pragma unroll
    for (int e = 0; e < 16; e++) {
        float wgt = rw[(size_t)n * 16 + e];
        const f32x4 pv = *(const f32x4*)(P + ((size_t)e * Nn + n) * Dd + d4);
        a0 += wgt * pv[0];
        a1 += wgt * pv[1];
        a2 += wgt * pv[2];
        a3 += wgt * pv[3];
    }
    u16x4 st = {f2bf(a0), f2bf(a1), f2bf(a2), f2bf(a3)};
    *(u16x4*)(outb + (size_t)n * Dd + d4) = st;
}

// ---------------- causal row softmax, in-place f32 -> bf16 ----------------
__global__ __launch_bounds__(256) void softmax_kernel(float* __restrict__ scores) {
    int i = blockIdx.x, b = blockIdx.y;
    float* row = scores + ((size_t)b * Tt + i) * Tt;
    int nv = i + 1;
    float v[8];
    int cnt = 0;
    float mx = -1e30f;
    for (int j = threadIdx.x; j < nv; j += 256) {
        float t = row[j];
        v[cnt++] = t;
        mx = fmaxf(mx, t);
    }
    __shared__ float sred[4];
    int w = threadIdx.x >> 6;
#pragma unroll
    for (int off = 32; off; off >>= 1) mx = fmaxf(mx, __shfl_down(mx, off));
    if ((threadIdx.x & 63) == 0) sred[w] = mx;
    __syncthreads();
    float m = fmaxf(fmaxf(sred[0], sred[1]), fmaxf(sred[2], sred[3]));
    float s = 0.f;
    for (int t = 0; t < cnt; t++) {
        v[t] = __expf(v[t] - m);
        s += v[t];
    }
    __syncthreads();  // sred reuse
#pragma unroll
    for (int off = 32; off; off >>= 1) s += __shfl_down(s, off);
    if ((threadIdx.x & 63) == 0) sred[w] = s;
    __syncthreads();
    float inv = 1.f / (sred[0] + sred[1] + sred[2] + sred[3]);
    unsigned short* prow = (unsigned short*)row;
    cnt = 0;
    for (int j = threadIdx.x; j < Tt; j += 256) {
        float pv = 0.f;
        if (j < nv) pv = v[cnt++] * inv;
        prow[j] = f2bf(pv);
    }
}

// ---------------- og[n, e*D+d] = rw[n,e] * o[n,d] ----------------
__global__ __launch_bounds__(256) void og_kernel(
    const float* __restrict__ ob, const float* __restrict__ rw,
    unsigned short* __restrict__ og) {
    int idx = blockIdx.x * 256 + threadIdx.x;  // (n, e, d4)
    int n = idx >> 9;
    int rem = idx & 511;
    int e = rem >> 5;
    int d4 = (rem & 31) << 2;
    float wgt = rw[(size_t)n * 16 + e];
    const f32x4 o4 = *(const f32x4*)(ob + (size_t)n * Dd + d4);
    u16x4 st = {f2bf(wgt * o4[0]), f2bf(wgt * o4[1]), f2bf(wgt * o4[2]), f2bf(wgt * o4[3])};
    *(u16x4*)(og + (size_t)n * (Ee * Dd) + e * Dd + d4) = st;
}

extern "C" void kernel_launch(void* const* d_in, const int* in_sizes, int n_in,
                              void* d_out, int out_size, void* d_ws, size_t ws_size,
                              hipStream_t stream) {
    (void)in_sizes; (void)n_in; (void)out_size; (void)ws_size;
    const float* hidden = (const float*)d_in[0];
    const float* sim = (const float*)d_in[1];
    const float* gates = (const float*)d_in[2];
    const float* qp = (const float*)d_in[3];
    const float* kp = (const float*)d_in[4];
    const float* vp = (const float*)d_in[5];
    const float* op = (const float*)d_in[6];
    const int* minex = (const int*)d_in[7];
    float* out = (float*)d_out;

    char* w = (char*)d_ws;
    size_t off = 0;
    auto alloc = [&](size_t bytes) -> char* {
        char* p = w + off;
        off = (off + bytes + 255) & ~(size_t)255;
        return p;
    };
    unsigned short* xb = (unsigned short*)alloc((size_t)Nn * Cch * 2);
    unsigned short* wqT = (unsigned short*)alloc((size_t)Ee * Dd * Cch * 2);
    unsigned short* wkT = (unsigned short*)alloc((size_t)Ee * Dd * Cch * 2);
    unsigned short* wvT = (unsigned short*)alloc((size_t)Ee * Dd * Cch * 2);
    unsigned short* woT = (unsigned short*)alloc((size_t)Cch * Ee * Dd * 2);
    float* rw = (float*)alloc((size_t)Nn * Ee * 4);
    float* sninv = (float*)alloc(256);
    char* big = alloc((size_t)Ee * Nn * Dd * 4);  // P buffers / scores / og share this
    unsigned short* qb = (unsigned short*)alloc((size_t)Nn * Dd * 2);
    unsigned short* kb = (unsigned short*)alloc((size_t)Nn * Dd * 2);
    unsigned short* vb = (unsigned short*)alloc((size_t)Nn * Dd * 2);
    unsigned short* vT = (unsigned short*)alloc((size_t)Bsz * Dd * Tt * 2);
    float* ob = (float*)alloc((size_t)Nn * Dd * 4);
    float* Pbuf = (float*)big;
    float* scores = (float*)big;
    unsigned short* og = (unsigned short*)big;

    const float scale = 0.08838834764831845f;  // 1/sqrt(128)

    colnorm_kernel<<<1, 256, 0, stream>>>(sim, sninv);
    gating_kernel<<<Nn, 256, 0, stream>>>(hidden, sim, gates, sninv, minex, rw, xb);

    // weight transposes (f32 -> bf16): [C,D] -> [D,C] per expert; o_proj [ED,C] -> [C,ED]
    transpose_f32_bf16<<<dim3(Dd / 32, Cch / 32, Ee), 256, 0, stream>>>(qp, wqT, Cch, Dd, (long)Cch * Dd, (long)Dd * Cch);
    transpose_f32_bf16<<<dim3(Dd / 32, Cch / 32, Ee), 256, 0, stream>>>(kp, wkT, Cch, Dd, (long)Cch * Dd, (long)Dd * Cch);
    transpose_f32_bf16<<<dim3(Dd / 32, Cch / 32, Ee), 256, 0, stream>>>(vp, wvT, Cch, Dd, (long)Cch * Dd, (long)Dd * Cch);
    transpose_f32_bf16<<<dim3((Ee * Dd) / 32, Cch / 32, 1), 256, 0, stream>>>(op, woT, Ee * Dd, Cch, 0L, 0L);

    // per-expert projections + routing-weighted combine
    dim3 gp(Nn / 128, 1, Ee);
    const int cgrid = Nn * Dd / 4 / 256;
    gemm_nt<0><<<gp, 256, 0, stream>>>(xb, 0L, Cch, wqT, (long)Dd * Cch, Cch, Pbuf, (long)Nn * Dd, Dd, Cch, 1.0f);
    combine_kernel<<<cgrid, 256, 0, stream>>>(Pbuf, rw, qb);
    gemm_nt<0><<<gp, 256, 0, stream>>>(xb, 0L, Cch, wkT, (long)Dd * Cch, Cch, Pbuf, (long)Nn * Dd, Dd, Cch, 1.0f);
    combine_kernel<<<cgrid, 256, 0, stream>>>(Pbuf, rw, kb);
    gemm_nt<0><<<gp, 256, 0, stream>>>(xb, 0L, Cch, wvT, (long)Dd * Cch, Cch, Pbuf, (long)Nn * Dd, Dd, Cch, 1.0f);
    combine_kernel<<<cgrid, 256, 0, stream>>>(Pbuf, rw, vb);

    // V transpose per batch for PV GEMM
    transpose_u16<<<dim3(Dd / 32, Tt / 32, Bsz), 256, 0, stream>>>(vb, vT, Tt, Dd, (long)Tt * Dd, (long)Dd * Tt);

    // scores = Q K^T * scale (causal), f32
    gemm_nt<1><<<dim3(Tt / 128, Tt / 128, Bsz), 256, 0, stream>>>(
        qb, (long)Tt * Dd, Dd, kb, (long)Tt * Dd, Dd, scores, (long)Tt * Tt, Tt, Dd, scale);
    // softmax (in-place bf16 P over the f32 scores rows)
    softmax_kernel<<<dim3(Tt, Bsz), 256, 0, stream>>>(scores);
    // O = P V   (P bf16 rows with element-stride 2T inside the f32 buffer)
    gemm_nt<0><<<dim3(Tt / 128, 1, Bsz), 256, 0, stream>>>(
        (const unsigned short*)scores, (long)2 * Tt * Tt, 2 * Tt, vT, (long)Dd * Tt, Tt, ob, (long)Tt * Dd, Dd, Tt, 1.0f);

    // og = rw-scaled o, expanded over experts; then single output GEMM
    og_kernel<<<(Nn * Ee * Dd / 4) / 256, 256, 0, stream>>>(ob, rw, og);
    gemm_nt<0><<<dim3(Nn / 128, Cch / 128, 1), 256, 0, stream>>>(
        og, 0L, Ee * Dd, woT, 0L, Ee * Dd, out, 0L, Cch, Ee * Dd, 1.0f);
}

// Round 2
// 636.309 us; speedup vs baseline: 1.1249x; 1.1249x over previous
//
#include <hip/hip_runtime.h>
#include <hip/hip_bf16.h>

#define DEV __device__ __forceinline__

typedef short bf16x8 __attribute__((ext_vector_type(8)));
typedef float f32x4 __attribute__((ext_vector_type(4)));
typedef unsigned short u16x4 __attribute__((ext_vector_type(4)));

static constexpr int Bsz = 4, Tt = 2048, Cch = 2048, Dd = 128, Ee = 16;
static constexpr int Nn = Bsz * Tt;
static constexpr int CAP = 4096;  // per-expert token capacity (mean ~1024, ~100 sigma margin)

DEV unsigned short f2bf(float v) {
    __hip_bfloat16 h = __float2bfloat16(v);
    return __builtin_bit_cast(unsigned short, h);
}
DEV float bf2f(unsigned short u) {
    unsigned int x = ((unsigned int)u) << 16;
    return __builtin_bit_cast(float, x);
}

// ---------------- sim_matrix column norms + cnt zeroing ----------------
__global__ __launch_bounds__(256) void colnorm_kernel(const float* __restrict__ sim,
                                                      float* __restrict__ sninv,
                                                      int* __restrict__ cnt) {
    if (threadIdx.x < 16) cnt[threadIdx.x] = 0;
    int e = threadIdx.x & 15, j = threadIdx.x >> 4;
    float ss = 0.f;
    for (int r = j; r < Cch; r += 16) {
        float v = sim[r * Ee + e];
        ss += v * v;
    }
    __shared__ float red[16][17];
    red[j][e] = ss;
    __syncthreads();
    if (threadIdx.x < 16) {
        float s = 0.f;
        for (int t = 0; t < 16; t++) s += red[t][threadIdx.x];
        sninv[threadIdx.x] = 1.f / fmaxf(sqrtf(s), 1e-12f);
    }
}

// ---------------- gating: routing weights, expert lists, bf16 cast of x ----------------
__global__ __launch_bounds__(256) void gating_kernel(
    const float* __restrict__ x, const float* __restrict__ sim,
    const float* __restrict__ gates, const float* __restrict__ sninv,
    const int* __restrict__ minex,
    float* __restrict__ rw, unsigned short* __restrict__ xb,
    int* __restrict__ cnt, int* __restrict__ idx, int* __restrict__ pos) {
    int n = blockIdx.x;
    const float* xr = x + (size_t)n * Cch;
    unsigned short* xbr = xb + (size_t)n * Cch;
    float ss = 0.f;
    float d[16];
#pragma unroll
    for (int e = 0; e < 16; e++) d[e] = 0.f;
    for (int c = threadIdx.x; c < Cch; c += 256) {
        float xv = xr[c];
        ss += xv * xv;
        xbr[c] = f2bf(xv);
        const float* srow = sim + (size_t)c * 16;
#pragma unroll
        for (int e = 0; e < 16; e++) d[e] += xv * srow[e];
    }
#pragma unroll
    for (int off = 32; off; off >>= 1) {
        ss += __shfl_down(ss, off);
#pragma unroll
        for (int e = 0; e < 16; e++) d[e] += __shfl_down(d[e], off);
    }
    __shared__ float red[4][17];
    int w = threadIdx.x >> 6, lane = threadIdx.x & 63;
    if (lane == 0) {
        red[w][16] = ss;
        for (int e = 0; e < 16; e++) red[w][e] = d[e];
    }
    __syncthreads();
    if (threadIdx.x == 0) {
        float S = red[0][16] + red[1][16] + red[2][16] + red[3][16];
        float inv = 1.f / fmaxf(sqrtf(S), 1e-12f);
        float logit[16];
        bool on[16];
        int nact = 0;
        for (int e = 0; e < 16; e++) {
            float dot = red[0][e] + red[1][e] + red[2][e] + red[3][e];
            float sg = 1.f / (1.f + __expf(-gates[e]));
            float l = dot * inv * sninv[e] - sg;
            logit[e] = l;
            on[e] = (l > 0.f);
            if (on[e]) nact++;
        }
        if (nact == 0) {
            int k = *minex;
            bool ch[16];
            for (int e = 0; e < 16; e++) ch[e] = false;
            for (int kk = 0; kk < k; kk++) {
                int best = -1;
                for (int e = 0; e < 16; e++)
                    if (!ch[e] && (best < 0 || logit[e] > logit[best])) best = e;
                ch[best] = true;
            }
            for (int e = 0; e < 16; e++) on[e] = ch[e];
        }
        float mx = -1e30f;
        for (int e = 0; e < 16; e++)
            if (on[e]) mx = fmaxf(mx, fmaxf(logit[e], 0.f));
        float p[16];
        float sum = 0.f;
        for (int e = 0; e < 16; e++) {
            p[e] = on[e] ? __expf(fmaxf(logit[e], 0.f) - mx) : 0.f;
            sum += p[e];
        }
        float isum = 1.f / sum;
        for (int e = 0; e < 16; e++) {
            rw[(size_t)n * 16 + e] = p[e] * isum;
            int pv = -1;
            if (on[e]) {
                int slot = atomicAdd(&cnt[e], 1);
                if (slot < CAP) {
                    idx[(size_t)e * CAP + slot] = n;
                    pv = slot;
                }
            }
            pos[(size_t)n * 16 + e] = pv;
        }
    }
}

// ---------------- transposes ----------------
// dst[x*R + y] = src[y*Ccol + x], x in grid.x*32, y in grid.y*32
__global__ __launch_bounds__(256) void transpose_f32_bf16(
    const float* __restrict__ src, unsigned short* __restrict__ dst,
    int R, int Ccol, long ss, long ds) {
    __shared__ float tile[32][33];
    src += (size_t)blockIdx.z * ss;
    dst += (size_t)blockIdx.z * ds;
    int bx = blockIdx.x * 32, by = blockIdx.y * 32;
    int tx = threadIdx.x & 31, ty = threadIdx.x >> 5;
#pragma unroll
    for (int i = 0; i < 4; i++)
        tile[ty + i * 8][tx] = src[(size_t)(by + ty + i * 8) * Ccol + bx + tx];
    __syncthreads();
#pragma unroll
    for (int i = 0; i < 4; i++)
        dst[(size_t)(bx + ty + i * 8) * R + by + tx] = f2bf(tile[tx][ty + i * 8]);
}

__global__ __launch_bounds__(256) void transpose_u16(
    const unsigned short* __restrict__ src, unsigned short* __restrict__ dst,
    int R, int Ccol, long ss, long ds) {
    __shared__ unsigned short tile[32][33];
    src += (size_t)blockIdx.z * ss;
    dst += (size_t)blockIdx.z * ds;
    int bx = blockIdx.x * 32, by = blockIdx.y * 32;
    int tx = threadIdx.x & 31, ty = threadIdx.x >> 5;
#pragma unroll
    for (int i = 0; i < 4; i++)
        tile[ty + i * 8][tx] = src[(size_t)(by + ty + i * 8) * Ccol + bx + tx];
    __syncthreads();
#pragma unroll
    for (int i = 0; i < 4; i++)
        dst[(size_t)(bx + ty + i * 8) * R + by + tx] = tile[tx][ty + i * 8];
}

// ---------------- NT GEMM: Out[M,N] = A[M,K] * BT[N,K]^T (bf16 in, f32 out) ----------------
// tile 128x128, BK=64, 4 waves of 64x64, 16x16x32 MFMA
template <int CAUSAL>
__global__ __launch_bounds__(256) void gemm_nt(
    const unsigned short* __restrict__ A, long strideA, int lda,
    const unsigned short* __restrict__ BT, long strideB, int ldb,
    float* __restrict__ Out, long strideO, int ldo,
    int K, float scale) {
    __shared__ alignas(16) unsigned short As[128 * 64];
    __shared__ alignas(16) unsigned short Bs[128 * 64];
    const int bm = blockIdx.x * 128;
    const int bn = blockIdx.y * 128;
    if (CAUSAL && bn > bm + 127) return;  // fully-masked causal tile
    A += (size_t)blockIdx.z * strideA;
    BT += (size_t)blockIdx.z * strideB;
    Out += (size_t)blockIdx.z * strideO;
    const int tid = threadIdx.x;
    const int wave = tid >> 6, lane = tid & 63;
    const int lr = lane & 15, lg = lane >> 4;
    const int wr = (wave >> 1) * 64, wc = (wave & 1) * 64;
    f32x4 acc[4][4] = {};

    for (int k0 = 0; k0 < K; k0 += 64) {
        __syncthreads();  // prior MFMA reads of LDS done
#pragma unroll
        for (int i = 0; i < 4; i++) {
            int t = i * 256 + tid;
            int row = t >> 3;
            int kc = (t & 7) << 3;
            __builtin_amdgcn_global_load_lds(
                (const __attribute__((address_space(1))) void*)(A + (size_t)(bm + row) * lda + k0 + kc),
                (__attribute__((address_space(3))) void*)(As + (i * 4 + wave) * 512),
                16, 0, 0);
        }
#pragma unroll
        for (int i = 0; i < 4; i++) {
            int t = i * 256 + tid;
            int row = t >> 3;
            int kc = (t & 7) << 3;
            __builtin_amdgcn_global_load_lds(
                (const __attribute__((address_space(1))) void*)(BT + (size_t)(bn + row) * ldb + k0 + kc),
                (__attribute__((address_space(3))) void*)(Bs + (i * 4 + wave) * 512),
                16, 0, 0);
        }
        __syncthreads();  // compiler drains vmcnt before barrier
#pragma unroll
        for (int kk = 0; kk < 2; kk++) {
            bf16x8 a[4], b[4];
#pragma unroll
            for (int m = 0; m < 4; m++)
                a[m] = *(const bf16x8*)(As + (wr + m * 16 + lr) * 64 + kk * 32 + lg * 8);
#pragma unroll
            for (int n = 0; n < 4; n++)
                b[n] = *(const bf16x8*)(Bs + (wc + n * 16 + lr) * 64 + kk * 32 + lg * 8);
#pragma unroll
            for (int m = 0; m < 4; m++)
#pragma unroll
                for (int n = 0; n < 4; n++)
                    acc[m][n] = __builtin_amdgcn_mfma_f32_16x16x32_bf16(a[m], b[n], acc[m][n], 0, 0, 0);
        }
    }
#pragma unroll
    for (int m = 0; m < 4; m++) {
#pragma unroll
        for (int n = 0; n < 4; n++) {
#pragma unroll
            for (int r = 0; r < 4; r++) {
                int grow = bm + wr + m * 16 + lg * 4 + r;
                int gcol = bn + wc + n * 16 + lr;
                if (!CAUSAL || gcol <= grow)
                    Out[(size_t)grow * ldo + gcol] = acc[m][n][r] * scale;
            }
        }
    }
}

// ---------------- gathered QKV projection: P[e][slot][384] = X[idx] @ Wqkv[e]^T ----------------
__global__ __launch_bounds__(256) void gemm_qkv_gather(
    const unsigned short* __restrict__ X,    // [Nn][C] bf16
    const unsigned short* __restrict__ W,    // [E][384][C] bf16 (rows = output dims)
    const int* __restrict__ idx, const int* __restrict__ cnt,
    unsigned short* __restrict__ P) {        // [E][CAP][384] bf16
    const int e = blockIdx.z;
    const int cn = min(cnt[e], CAP);
    const int bm = blockIdx.x * 128;
    if (bm >= cn) return;
    const int bn = blockIdx.y * 128;
    __shared__ alignas(16) unsigned short As[128 * 64];
    __shared__ alignas(16) unsigned short Bs[128 * 64];
    __shared__ int toks[128];
    const int tid = threadIdx.x;
    if (tid < 128) toks[tid] = idx[(size_t)e * CAP + min(bm + tid, cn - 1)];
    const unsigned short* Wb = W + ((size_t)e * 384 + bn) * Cch;
    const int wave = tid >> 6, lane = tid & 63;
    const int lr = lane & 15, lg = lane >> 4;
    const int wr = (wave >> 1) * 64, wc = (wave & 1) * 64;
    f32x4 acc[4][4] = {};

    for (int k0 = 0; k0 < Cch; k0 += 64) {
        __syncthreads();
#pragma unroll
        for (int i = 0; i < 4; i++) {
            int t = i * 256 + tid;
            int row = t >> 3;
            int kc = (t & 7) << 3;
            __builtin_amdgcn_global_load_lds(
                (const __attribute__((address_space(1))) void*)(X + (size_t)toks[row] * Cch + k0 + kc),
                (__attribute__((address_space(3))) void*)(As + (i * 4 + wave) * 512),
                16, 0, 0);
        }
#pragma unroll
        for (int i = 0; i < 4; i++) {
            int t = i * 256 + tid;
            int row = t >> 3;
            int kc = (t & 7) << 3;
            __builtin_amdgcn_global_load_lds(
                (const __attribute__((address_space(1))) void*)(Wb + (size_t)row * Cch + k0 + kc),
                (__attribute__((address_space(3))) void*)(Bs + (i * 4 + wave) * 512),
                16, 0, 0);
        }
        __syncthreads();
#pragma unroll
        for (int kk = 0; kk < 2; kk++) {
            bf16x8 a[4], b[4];
#pragma unroll
            for (int m = 0; m < 4; m++)
                a[m] = *(const bf16x8*)(As + (wr + m * 16 + lr) * 64 + kk * 32 + lg * 8);
#pragma unroll
            for (int n = 0; n < 4; n++)
                b[n] = *(const bf16x8*)(Bs + (wc + n * 16 + lr) * 64 + kk * 32 + lg * 8);
#pragma unroll
            for (int m = 0; m < 4; m++)
#pragma unroll
                for (int n = 0; n < 4; n++)
                    acc[m][n] = __builtin_amdgcn_mfma_f32_16x16x32_bf16(a[m], b[n], acc[m][n], 0, 0, 0);
        }
    }
#pragma unroll
    for (int m = 0; m < 4; m++) {
#pragma unroll
        for (int n = 0; n < 4; n++) {
#pragma unroll
            for (int r = 0; r < 4; r++) {
                int slot = bm + wr + m * 16 + lg * 4 + r;
                int col = bn + wc + n * 16 + lr;
                if (slot < cn)
                    P[((size_t)e * CAP + slot) * 384 + col] = f2bf(acc[m][n][r]);
            }
        }
    }
}

// ---------------- combine: q/k/v[n,d] = sum_e rw[n,e] * P[e, pos[n,e], {d, 128+d, 256+d}] ----------------
__global__ __launch_bounds__(256) void combine_qkv(
    const unsigned short* __restrict__ P, const float* __restrict__ rw,
    const int* __restrict__ pos,
    unsigned short* __restrict__ qb, unsigned short* __restrict__ kb,
    unsigned short* __restrict__ vb) {
    int i = blockIdx.x * 256 + threadIdx.x;  // (n, d4)
    int n = i >> 5;
    int d4 = (i & 31) << 2;
    float aq[4] = {}, ak[4] = {}, av[4] = {};
#pragma unroll
    for (int e = 0; e < 16; e++) {
        int p = pos[(size_t)n * 16 + e];
        if (p >= 0) {
            float w = rw[(size_t)n * 16 + e];
            const unsigned short* row = P + ((size_t)e * CAP + p) * 384 + d4;
            const u16x4 q4 = *(const u16x4*)(row);
            const u16x4 k4 = *(const u16x4*)(row + 128);
            const u16x4 v4 = *(const u16x4*)(row + 256);
#pragma unroll
            for (int j = 0; j < 4; j++) {
                aq[j] += w * bf2f(q4[j]);
                ak[j] += w * bf2f(k4[j]);
                av[j] += w * bf2f(v4[j]);
            }
        }
    }
    u16x4 sq = {f2bf(aq[0]), f2bf(aq[1]), f2bf(aq[2]), f2bf(aq[3])};
    u16x4 sk = {f2bf(ak[0]), f2bf(ak[1]), f2bf(ak[2]), f2bf(ak[3])};
    u16x4 sv = {f2bf(av[0]), f2bf(av[1]), f2bf(av[2]), f2bf(av[3])};
    *(u16x4*)(qb + (size_t)n * Dd + d4) = sq;
    *(u16x4*)(kb + (size_t)n * Dd + d4) = sk;
    *(u16x4*)(vb + (size_t)n * Dd + d4) = sv;
}

// ---------------- causal row softmax, in-place f32 -> bf16 ----------------
__global__ __launch_bounds__(256) void softmax_kernel(float* __restrict__ scores) {
    int i = blockIdx.x, b = blockIdx.y;
    float* row = scores + ((size_t)b * Tt + i) * Tt;
    int nv = i + 1;
    float v[8];
    int cnt = 0;
    float mx = -1e30f;
    for (int j = threadIdx.x; j < nv; j += 256) {
        float t = row[j];
        v[cnt++] = t;
        mx = fmaxf(mx, t);
    }
    __shared__ float sred[4];
    int w = threadIdx.x >> 6;
#pragma unroll
    for (int off = 32; off; off >>= 1) mx = fmaxf(mx, __shfl_down(mx, off));
    if ((threadIdx.x & 63) == 0) sred[w] = mx;
    __syncthreads();
    float m = fmaxf(fmaxf(sred[0], sred[1]), fmaxf(sred[2], sred[3]));
    float s = 0.f;
    for (int t = 0; t < cnt; t++) {
        v[t] = __expf(v[t] - m);
        s += v[t];
    }
    __syncthreads();  // sred reuse
#pragma unroll
    for (int off = 32; off; off >>= 1) s += __shfl_down(s, off);
    if ((threadIdx.x & 63) == 0) sred[w] = s;
    __syncthreads();
    float inv = 1.f / (sred[0] + sred[1] + sred[2] + sred[3]);
    unsigned short* prow = (unsigned short*)row;
    cnt = 0;
    for (int j = threadIdx.x; j < Tt; j += 256) {
        float pv = 0.f;
        if (j < nv) pv = v[cnt++] * inv;
        prow[j] = f2bf(pv);
    }
}

// ---------------- og[n, e*D+d] = rw[n,e] * o[n,d] ----------------
__global__ __launch_bounds__(256) void og_kernel(
    const float* __restrict__ ob, const float* __restrict__ rw,
    unsigned short* __restrict__ og) {
    int idx = blockIdx.x * 256 + threadIdx.x;  // (n, e, d4)
    int n = idx >> 9;
    int rem = idx & 511;
    int e = rem >> 5;
    int d4 = (rem & 31) << 2;
    float wgt = rw[(size_t)n * 16 + e];
    const f32x4 o4 = *(const f32x4*)(ob + (size_t)n * Dd + d4);
    u16x4 st = {f2bf(wgt * o4[0]), f2bf(wgt * o4[1]), f2bf(wgt * o4[2]), f2bf(wgt * o4[3])};
    *(u16x4*)(og + (size_t)n * (Ee * Dd) + e * Dd + d4) = st;
}

extern "C" void kernel_launch(void* const* d_in, const int* in_sizes, int n_in,
                              void* d_out, int out_size, void* d_ws, size_t ws_size,
                              hipStream_t stream) {
    (void)in_sizes; (void)n_in; (void)out_size; (void)ws_size;
    const float* hidden = (const float*)d_in[0];
    const float* sim = (const float*)d_in[1];
    const float* gates = (const float*)d_in[2];
    const float* qp = (const float*)d_in[3];
    const float* kp = (const float*)d_in[4];
    const float* vp = (const float*)d_in[5];
    const float* op = (const float*)d_in[6];
    const int* minex = (const int*)d_in[7];
    float* out = (float*)d_out;

    char* w = (char*)d_ws;
    size_t off = 0;
    auto alloc = [&](size_t bytes) -> char* {
        char* p = w + off;
        off = (off + bytes + 255) & ~(size_t)255;
        return p;
    };
    unsigned short* xb = (unsigned short*)alloc((size_t)Nn * Cch * 2);
    unsigned short* wqkvT = (unsigned short*)alloc((size_t)Ee * 384 * Cch * 2);
    unsigned short* woT = (unsigned short*)alloc((size_t)Cch * Ee * Dd * 2);
    float* rw = (float*)alloc((size_t)Nn * Ee * 4);
    float* sninv = (float*)alloc(256);
    int* cnt = (int*)alloc(64 * 4);
    int* idx = (int*)alloc((size_t)Ee * CAP * 4);
    int* pos = (int*)alloc((size_t)Nn * 16 * 4);
    char* big = alloc((size_t)Bsz * Tt * Tt * 4);  // P-compact / scores / og share this
    unsigned short* qb = (unsigned short*)alloc((size_t)Nn * Dd * 2);
    unsigned short* kb = (unsigned short*)alloc((size_t)Nn * Dd * 2);
    unsigned short* vb = (unsigned short*)alloc((size_t)Nn * Dd * 2);
    unsigned short* vT = (unsigned short*)alloc((size_t)Bsz * Dd * Tt * 2);
    float* ob = (float*)alloc((size_t)Nn * Dd * 4);
    unsigned short* Pc = (unsigned short*)big;   // [E][CAP][384] bf16 = 50.3 MB
    float* scores = (float*)big;                 // [B][T][T] f32 = 67 MB
    unsigned short* og = (unsigned short*)big;   // [Nn][E*D] bf16 = 33.5 MB

    const float scale = 0.08838834764831845f;  // 1/sqrt(128)

    colnorm_kernel<<<1, 256, 0, stream>>>(sim, sninv, cnt);
    gating_kernel<<<Nn, 256, 0, stream>>>(hidden, sim, gates, sninv, minex, rw, xb, cnt, idx, pos);

    // weight transposes (f32 -> bf16) into fused [E][384][C] (rows 0-127 q, 128-255 k, 256-383 v)
    transpose_f32_bf16<<<dim3(Dd / 32, Cch / 32, Ee), 256, 0, stream>>>(
        qp, wqkvT + 0 * Dd * Cch, Cch, Dd, (long)Cch * Dd, (long)384 * Cch);
    transpose_f32_bf16<<<dim3(Dd / 32, Cch / 32, Ee), 256, 0, stream>>>(
        kp, wqkvT + 1 * Dd * Cch, Cch, Dd, (long)Cch * Dd, (long)384 * Cch);
    transpose_f32_bf16<<<dim3(Dd / 32, Cch / 32, Ee), 256, 0, stream>>>(
        vp, wqkvT + 2 * Dd * Cch, Cch, Dd, (long)Cch * Dd, (long)384 * Cch);
    transpose_f32_bf16<<<dim3((Ee * Dd) / 32, Cch / 32, 1), 256, 0, stream>>>(
        op, woT, Ee * Dd, Cch, 0L, 0L);

    // gathered per-expert QKV projection (only active tokens), then combine
    gemm_qkv_gather<<<dim3(CAP / 128, 3, Ee), 256, 0, stream>>>(xb, wqkvT, idx, cnt, Pc);
    combine_qkv<<<(Nn * 32) / 256, 256, 0, stream>>>(Pc, rw, pos, qb, kb, vb);

    // V transpose per batch for PV GEMM
    transpose_u16<<<dim3(Dd / 32, Tt / 32, Bsz), 256, 0, stream>>>(
        vb, vT, Tt, Dd, (long)Tt * Dd, (long)Dd * Tt);

    // scores = Q K^T * scale (causal), f32
    gemm_nt<1><<<dim3(Tt / 128, Tt / 128, Bsz), 256, 0, stream>>>(
        qb, (long)Tt * Dd, Dd, kb, (long)Tt * Dd, Dd, scores, (long)Tt * Tt, Tt, Dd, scale);
    // softmax (in-place bf16 P over the f32 scores rows)
    softmax_kernel<<<dim3(Tt, Bsz), 256, 0, stream>>>(scores);
    // O = P V   (P bf16 rows with element-stride 2T inside the f32 buffer)
    gemm_nt<0><<<dim3(Tt / 128, 1, Bsz), 256, 0, stream>>>(
        (const unsigned short*)scores, (long)2 * Tt * Tt, 2 * Tt, vT, (long)Dd * Tt, Tt,
        ob, (long)Tt * Dd, Dd, Tt, 1.0f);

    // og = rw-scaled o, expanded over experts; then single output GEMM
    og_kernel<<<(Nn * Ee * Dd / 4) / 256, 256, 0, stream>>>(ob, rw, og);
    gemm_nt<0><<<dim3(Nn / 128, Cch / 128, 1), 256, 0, stream>>>(
        og, 0L, Ee * Dd, woT, 0L, Ee * Dd, out, 0L, Cch, Ee * Dd, 1.0f);
}

// Round 3
// 628.795 us; speedup vs baseline: 1.1383x; 1.0119x over previous
//
#include <hip/hip_runtime.h>
#include <hip/hip_bf16.h>

#define DEV __device__ __forceinline__

typedef short bf16x8 __attribute__((ext_vector_type(8)));
typedef float f32x4 __attribute__((ext_vector_type(4)));
typedef unsigned short u16x4 __attribute__((ext_vector_type(4)));

static constexpr int Bsz = 4, Tt = 2048, Cch = 2048, Dd = 128, Ee = 16;
static constexpr int Nn = Bsz * Tt;
static constexpr int CAP = 4096;  // per-expert token capacity (mean ~1024)

DEV unsigned short f2bf(float v) {
    __hip_bfloat16 h = __float2bfloat16(v);
    return __builtin_bit_cast(unsigned short, h);
}
DEV float bf2f(unsigned short u) {
    unsigned int x = ((unsigned int)u) << 16;
    return __builtin_bit_cast(float, x);
}

// ---------------- sim_matrix column norms + cnt zeroing ----------------
__global__ __launch_bounds__(256) void colnorm_kernel(const float* __restrict__ sim,
                                                      float* __restrict__ sninv,
                                                      int* __restrict__ cnt) {
    if (threadIdx.x < 16) cnt[threadIdx.x] = 0;
    int e = threadIdx.x & 15, j = threadIdx.x >> 4;
    float ss = 0.f;
    for (int r = j; r < Cch; r += 16) {
        float v = sim[r * Ee + e];
        ss += v * v;
    }
    __shared__ float red[16][17];
    red[j][e] = ss;
    __syncthreads();
    if (threadIdx.x < 16) {
        float s = 0.f;
        for (int t = 0; t < 16; t++) s += red[t][threadIdx.x];
        sninv[threadIdx.x] = 1.f / fmaxf(sqrtf(s), 1e-12f);
    }
}

// ---------------- sim transpose: simT[e][c] = sim[c][e] ----------------
__global__ __launch_bounds__(256) void simt_kernel(const float* __restrict__ sim,
                                                   float* __restrict__ simT) {
    int i = blockIdx.x * 256 + threadIdx.x;  // 16*2048
    int e = i >> 11, c = i & 2047;
    simT[i] = sim[c * 16 + e];
}

// ---------------- gating: 1 wave per token, vectorized via simT ----------------
__global__ __launch_bounds__(256) void gating2_kernel(
    const float* __restrict__ x, const float* __restrict__ simT,
    const float* __restrict__ gates, const float* __restrict__ sninv,
    const int* __restrict__ minex,
    float* __restrict__ rw, unsigned short* __restrict__ xb,
    int* __restrict__ cnt, int* __restrict__ idx, int* __restrict__ pos) {
    const int wave = threadIdx.x >> 6, lane = threadIdx.x & 63;
    const int n = blockIdx.x * 4 + wave;
    const f32x4* xr = (const f32x4*)(x + (size_t)n * Cch);
    const f32x4* st = (const f32x4*)simT;
    u16x4* xbr = (u16x4*)(xb + (size_t)n * Cch);
    float ss = 0.f;
    float d[16];
#pragma unroll
    for (int e = 0; e < 16; e++) d[e] = 0.f;
#pragma unroll
    for (int it = 0; it < 8; it++) {
        int i = it * 64 + lane;
        f32x4 xv = xr[i];
        ss += xv[0] * xv[0] + xv[1] * xv[1] + xv[2] * xv[2] + xv[3] * xv[3];
        u16x4 xc = {f2bf(xv[0]), f2bf(xv[1]), f2bf(xv[2]), f2bf(xv[3])};
        xbr[i] = xc;
#pragma unroll
        for (int e = 0; e < 16; e++) {
            f32x4 sv = st[e * 512 + i];
            d[e] += xv[0] * sv[0] + xv[1] * sv[1] + xv[2] * sv[2] + xv[3] * sv[3];
        }
    }
#pragma unroll
    for (int off = 32; off; off >>= 1) {
        ss += __shfl_down(ss, off);
#pragma unroll
        for (int e = 0; e < 16; e++) d[e] += __shfl_down(d[e], off);
    }
    if (lane == 0) {
        float inv = 1.f / fmaxf(sqrtf(ss), 1e-12f);
        float logit[16];
        int onmask = 0;
#pragma unroll
        for (int e = 0; e < 16; e++) {
            float sg = 1.f / (1.f + __expf(-gates[e]));
            float l = d[e] * inv * sninv[e] - sg;
            logit[e] = l;
            if (l > 0.f) onmask |= (1 << e);
        }
        if (onmask == 0) {
            int k = *minex;
            int ch = 0;
            for (int kk = 0; kk < k; kk++) {
                float bv = -1e30f;
                int be = 0;
#pragma unroll
                for (int e = 0; e < 16; e++)
                    if (!((ch >> e) & 1) && logit[e] > bv) { bv = logit[e]; be = e; }
                ch |= (1 << be);
            }
            onmask = ch;
        }
        float mx = -1e30f;
#pragma unroll
        for (int e = 0; e < 16; e++)
            if ((onmask >> e) & 1) mx = fmaxf(mx, fmaxf(logit[e], 0.f));
        float pe[16];
        float sum = 0.f;
#pragma unroll
        for (int e = 0; e < 16; e++) {
            pe[e] = ((onmask >> e) & 1) ? __expf(fmaxf(logit[e], 0.f) - mx) : 0.f;
            sum += pe[e];
        }
        float isum = 1.f / sum;
#pragma unroll
        for (int e = 0; e < 16; e++) {
            rw[(size_t)n * 16 + e] = pe[e] * isum;
            int pv = -1;
            if ((onmask >> e) & 1) {
                int slot = atomicAdd(&cnt[e], 1);
                if (slot < CAP) {
                    idx[(size_t)e * CAP + slot] = n;
                    pv = slot;
                }
            }
            pos[(size_t)n * 16 + e] = pv;
        }
    }
}

// ---------------- transposes ----------------
__global__ __launch_bounds__(256) void transpose_f32_bf16(
    const float* __restrict__ src, unsigned short* __restrict__ dst,
    int R, int Ccol, long ss, long ds) {
    __shared__ float tile[32][33];
    src += (size_t)blockIdx.z * ss;
    dst += (size_t)blockIdx.z * ds;
    int bx = blockIdx.x * 32, by = blockIdx.y * 32;
    int tx = threadIdx.x & 31, ty = threadIdx.x >> 5;
#pragma unroll
    for (int i = 0; i < 4; i++)
        tile[ty + i * 8][tx] = src[(size_t)(by + ty + i * 8) * Ccol + bx + tx];
    __syncthreads();
#pragma unroll
    for (int i = 0; i < 4; i++)
        dst[(size_t)(bx + ty + i * 8) * R + by + tx] = f2bf(tile[tx][ty + i * 8]);
}

__global__ __launch_bounds__(256) void transpose_u16(
    const unsigned short* __restrict__ src, unsigned short* __restrict__ dst,
    int R, int Ccol, long ss, long ds) {
    __shared__ unsigned short tile[32][33];
    src += (size_t)blockIdx.z * ss;
    dst += (size_t)blockIdx.z * ds;
    int bx = blockIdx.x * 32, by = blockIdx.y * 32;
    int tx = threadIdx.x & 31, ty = threadIdx.x >> 5;
#pragma unroll
    for (int i = 0; i < 4; i++)
        tile[ty + i * 8][tx] = src[(size_t)(by + ty + i * 8) * Ccol + bx + tx];
    __syncthreads();
#pragma unroll
    for (int i = 0; i < 4; i++)
        dst[(size_t)(bx + ty + i * 8) * R + by + tx] = tile[tx][ty + i * 8];
}

// ---------------- NT GEMM: Out[M,N] = A[M,K] * BT[N,K]^T (bf16 in, f32 out) ----------------
template <int CAUSAL>
__global__ __launch_bounds__(256) void gemm_nt(
    const unsigned short* __restrict__ A, long strideA, int lda,
    const unsigned short* __restrict__ BT, long strideB, int ldb,
    float* __restrict__ Out, long strideO, int ldo,
    int K, float scale) {
    __shared__ alignas(16) unsigned short As[128 * 64];
    __shared__ alignas(16) unsigned short Bs[128 * 64];
    const int bm = blockIdx.x * 128;
    const int bn = blockIdx.y * 128;
    if (CAUSAL && bn > bm + 127) return;
    A += (size_t)blockIdx.z * strideA;
    BT += (size_t)blockIdx.z * strideB;
    Out += (size_t)blockIdx.z * strideO;
    const int tid = threadIdx.x;
    const int wave = tid >> 6, lane = tid & 63;
    const int lr = lane & 15, lg = lane >> 4;
    const int wr = (wave >> 1) * 64, wc = (wave & 1) * 64;
    f32x4 acc[4][4] = {};

    for (int k0 = 0; k0 < K; k0 += 64) {
        __syncthreads();
#pragma unroll
        for (int i = 0; i < 4; i++) {
            int t = i * 256 + tid;
            int row = t >> 3;
            int kc = (t & 7) << 3;
            __builtin_amdgcn_global_load_lds(
                (const __attribute__((address_space(1))) void*)(A + (size_t)(bm + row) * lda + k0 + kc),
                (__attribute__((address_space(3))) void*)(As + (i * 4 + wave) * 512),
                16, 0, 0);
        }
#pragma unroll
        for (int i = 0; i < 4; i++) {
            int t = i * 256 + tid;
            int row = t >> 3;
            int kc = (t & 7) << 3;
            __builtin_amdgcn_global_load_lds(
                (const __attribute__((address_space(1))) void*)(BT + (size_t)(bn + row) * ldb + k0 + kc),
                (__attribute__((address_space(3))) void*)(Bs + (i * 4 + wave) * 512),
                16, 0, 0);
        }
        __syncthreads();
#pragma unroll
        for (int kk = 0; kk < 2; kk++) {
            bf16x8 a[4], b[4];
#pragma unroll
            for (int m = 0; m < 4; m++)
                a[m] = *(const bf16x8*)(As + (wr + m * 16 + lr) * 64 + kk * 32 + lg * 8);
#pragma unroll
            for (int n = 0; n < 4; n++)
                b[n] = *(const bf16x8*)(Bs + (wc + n * 16 + lr) * 64 + kk * 32 + lg * 8);
#pragma unroll
            for (int m = 0; m < 4; m++)
#pragma unroll
                for (int n = 0; n < 4; n++)
                    acc[m][n] = __builtin_amdgcn_mfma_f32_16x16x32_bf16(a[m], b[n], acc[m][n], 0, 0, 0);
        }
    }
#pragma unroll
    for (int m = 0; m < 4; m++) {
#pragma unroll
        for (int n = 0; n < 4; n++) {
#pragma unroll
            for (int r = 0; r < 4; r++) {
                int grow = bm + wr + m * 16 + lg * 4 + r;
                int gcol = bn + wc + n * 16 + lr;
                if (!CAUSAL || gcol <= grow)
                    Out[(size_t)grow * ldo + gcol] = acc[m][n][r] * scale;
            }
        }
    }
}

// ---------------- PV GEMM: split-K over causal-active chunks, atomic f32 accumulate ----------------
// P rows: bf16 packed in first half of f32 score rows (row stride 4096 u16); vT [B][D][T]
__global__ __launch_bounds__(256) void gemm_pv(
    const unsigned short* __restrict__ P, const unsigned short* __restrict__ vT,
    float* __restrict__ ob) {
    const int bm = blockIdx.x * 128;
    const int kb = blockIdx.y * 512;
    if (kb > bm + 127) return;  // keys entirely above diagonal -> P block is all zero
    const unsigned short* Pb = P + (size_t)blockIdx.z * Tt * 4096;
    const unsigned short* Vb = vT + (size_t)blockIdx.z * Dd * Tt;
    float* Ob = ob + (size_t)blockIdx.z * Tt * Dd;
    __shared__ alignas(16) unsigned short As[128 * 64];
    __shared__ alignas(16) unsigned short Bs[128 * 64];
    const int tid = threadIdx.x;
    const int wave = tid >> 6, lane = tid & 63;
    const int lr = lane & 15, lg = lane >> 4;
    const int wr = (wave >> 1) * 64, wc = (wave & 1) * 64;
    f32x4 acc[4][4] = {};

    for (int k0 = kb; k0 < kb + 512; k0 += 64) {
        __syncthreads();
#pragma unroll
        for (int i = 0; i < 4; i++) {
            int t = i * 256 + tid;
            int row = t >> 3;
            int kc = (t & 7) << 3;
            __builtin_amdgcn_global_load_lds(
                (const __attribute__((address_space(1))) void*)(Pb + (size_t)(bm + row) * 4096 + k0 + kc),
                (__attribute__((address_space(3))) void*)(As + (i * 4 + wave) * 512),
                16, 0, 0);
        }
#pragma unroll
        for (int i = 0; i < 4; i++) {
            int t = i * 256 + tid;
            int row = t >> 3;
            int kc = (t & 7) << 3;
            __builtin_amdgcn_global_load_lds(
                (const __attribute__((address_space(1))) void*)(Vb + (size_t)row * Tt + k0 + kc),
                (__attribute__((address_space(3))) void*)(Bs + (i * 4 + wave) * 512),
                16, 0, 0);
        }
        __syncthreads();
#pragma unroll
        for (int kk = 0; kk < 2; kk++) {
            bf16x8 a[4], b[4];
#pragma unroll
            for (int m = 0; m < 4; m++)
                a[m] = *(const bf16x8*)(As + (wr + m * 16 + lr) * 64 + kk * 32 + lg * 8);
#pragma unroll
            for (int n = 0; n < 4; n++)
                b[n] = *(const bf16x8*)(Bs + (wc + n * 16 + lr) * 64 + kk * 32 + lg * 8);
#pragma unroll
            for (int m = 0; m < 4; m++)
#pragma unroll
                for (int n = 0; n < 4; n++)
                    acc[m][n] = __builtin_amdgcn_mfma_f32_16x16x32_bf16(a[m], b[n], acc[m][n], 0, 0, 0);
        }
    }
#pragma unroll
    for (int m = 0; m < 4; m++)
#pragma unroll
        for (int n = 0; n < 4; n++)
#pragma unroll
            for (int r = 0; r < 4; r++) {
                int grow = bm + wr + m * 16 + lg * 4 + r;
                int gcol = wc + n * 16 + lr;
                atomicAdd(&Ob[(size_t)grow * Dd + gcol], acc[m][n][r]);
            }
}

// ---------------- gathered QKV projection ----------------
__global__ __launch_bounds__(256) void gemm_qkv_gather(
    const unsigned short* __restrict__ X, const unsigned short* __restrict__ W,
    const int* __restrict__ idx, const int* __restrict__ cnt,
    unsigned short* __restrict__ P) {
    const int e = blockIdx.z;
    const int cn = min(cnt[e], CAP);
    const int bm = blockIdx.x * 128;
    if (bm >= cn) return;
    const int bn = blockIdx.y * 128;
    __shared__ alignas(16) unsigned short As[128 * 64];
    __shared__ alignas(16) unsigned short Bs[128 * 64];
    __shared__ int toks[128];
    const int tid = threadIdx.x;
    if (tid < 128) toks[tid] = idx[(size_t)e * CAP + min(bm + tid, cn - 1)];
    const unsigned short* Wb = W + ((size_t)e * 384 + bn) * Cch;
    const int wave = tid >> 6, lane = tid & 63;
    const int lr = lane & 15, lg = lane >> 4;
    const int wr = (wave >> 1) * 64, wc = (wave & 1) * 64;
    f32x4 acc[4][4] = {};

    for (int k0 = 0; k0 < Cch; k0 += 64) {
        __syncthreads();
#pragma unroll
        for (int i = 0; i < 4; i++) {
            int t = i * 256 + tid;
            int row = t >> 3;
            int kc = (t & 7) << 3;
            __builtin_amdgcn_global_load_lds(
                (const __attribute__((address_space(1))) void*)(X + (size_t)toks[row] * Cch + k0 + kc),
                (__attribute__((address_space(3))) void*)(As + (i * 4 + wave) * 512),
                16, 0, 0);
        }
#pragma unroll
        for (int i = 0; i < 4; i++) {
            int t = i * 256 + tid;
            int row = t >> 3;
            int kc = (t & 7) << 3;
            __builtin_amdgcn_global_load_lds(
                (const __attribute__((address_space(1))) void*)(Wb + (size_t)row * Cch + k0 + kc),
                (__attribute__((address_space(3))) void*)(Bs + (i * 4 + wave) * 512),
                16, 0, 0);
        }
        __syncthreads();
#pragma unroll
        for (int kk = 0; kk < 2; kk++) {
            bf16x8 a[4], b[4];
#pragma unroll
            for (int m = 0; m < 4; m++)
                a[m] = *(const bf16x8*)(As + (wr + m * 16 + lr) * 64 + kk * 32 + lg * 8);
#pragma unroll
            for (int n = 0; n < 4; n++)
                b[n] = *(const bf16x8*)(Bs + (wc + n * 16 + lr) * 64 + kk * 32 + lg * 8);
#pragma unroll
            for (int m = 0; m < 4; m++)
#pragma unroll
                for (int n = 0; n < 4; n++)
                    acc[m][n] = __builtin_amdgcn_mfma_f32_16x16x32_bf16(a[m], b[n], acc[m][n], 0, 0, 0);
        }
    }
#pragma unroll
    for (int m = 0; m < 4; m++)
#pragma unroll
        for (int n = 0; n < 4; n++)
#pragma unroll
            for (int r = 0; r < 4; r++) {
                int slot = bm + wr + m * 16 + lg * 4 + r;
                int col = bn + wc + n * 16 + lr;
                if (slot < cn)
                    P[((size_t)e * CAP + slot) * 384 + col] = f2bf(acc[m][n][r]);
            }
}

// ---------------- combine q/k/v ----------------
__global__ __launch_bounds__(256) void combine_qkv(
    const unsigned short* __restrict__ P, const float* __restrict__ rw,
    const int* __restrict__ pos,
    unsigned short* __restrict__ qb, unsigned short* __restrict__ kb,
    unsigned short* __restrict__ vb) {
    int i = blockIdx.x * 256 + threadIdx.x;
    int n = i >> 5;
    int d4 = (i & 31) << 2;
    float aq[4] = {}, ak[4] = {}, av[4] = {};
#pragma unroll
    for (int e = 0; e < 16; e++) {
        int p = pos[(size_t)n * 16 + e];
        if (p >= 0) {
            float w = rw[(size_t)n * 16 + e];
            const unsigned short* row = P + ((size_t)e * CAP + p) * 384 + d4;
            const u16x4 q4 = *(const u16x4*)(row);
            const u16x4 k4 = *(const u16x4*)(row + 128);
            const u16x4 v4 = *(const u16x4*)(row + 256);
#pragma unroll
            for (int j = 0; j < 4; j++) {
                aq[j] += w * bf2f(q4[j]);
                ak[j] += w * bf2f(k4[j]);
                av[j] += w * bf2f(v4[j]);
            }
        }
    }
    u16x4 sq = {f2bf(aq[0]), f2bf(aq[1]), f2bf(aq[2]), f2bf(aq[3])};
    u16x4 sk = {f2bf(ak[0]), f2bf(ak[1]), f2bf(ak[2]), f2bf(ak[3])};
    u16x4 sv = {f2bf(av[0]), f2bf(av[1]), f2bf(av[2]), f2bf(av[3])};
    *(u16x4*)(qb + (size_t)n * Dd + d4) = sq;
    *(u16x4*)(kb + (size_t)n * Dd + d4) = sk;
    *(u16x4*)(vb + (size_t)n * Dd + d4) = sv;
}

// ---------------- causal row softmax, in-place f32 -> bf16 ----------------
__global__ __launch_bounds__(256) void softmax_kernel(float* __restrict__ scores) {
    int i = blockIdx.x, b = blockIdx.y;
    float* row = scores + ((size_t)b * Tt + i) * Tt;
    int nv = i + 1;
    float v[8];
    int cnt = 0;
    float mx = -1e30f;
    for (int j = threadIdx.x; j < nv; j += 256) {
        float t = row[j];
        v[cnt++] = t;
        mx = fmaxf(mx, t);
    }
    __shared__ float sred[4];
    int w = threadIdx.x >> 6;
#pragma unroll
    for (int off = 32; off; off >>= 1) mx = fmaxf(mx, __shfl_down(mx, off));
    if ((threadIdx.x & 63) == 0) sred[w] = mx;
    __syncthreads();
    float m = fmaxf(fmaxf(sred[0], sred[1]), fmaxf(sred[2], sred[3]));
    float s = 0.f;
    for (int t = 0; t < cnt; t++) {
        v[t] = __expf(v[t] - m);
        s += v[t];
    }
    __syncthreads();
#pragma unroll
    for (int off = 32; off; off >>= 1) s += __shfl_down(s, off);
    if ((threadIdx.x & 63) == 0) sred[w] = s;
    __syncthreads();
    float inv = 1.f / (sred[0] + sred[1] + sred[2] + sred[3]);
    unsigned short* prow = (unsigned short*)row;
    cnt = 0;
    for (int j = threadIdx.x; j < Tt; j += 256) {
        float pv = 0.f;
        if (j < nv) pv = v[cnt++] * inv;
        prow[j] = f2bf(pv);
    }
}

// ---------------- og[n, e*D+d] = rw[n,e] * o[n,d] ----------------
__global__ __launch_bounds__(256) void og_kernel(
    const float* __restrict__ ob, const float* __restrict__ rw,
    unsigned short* __restrict__ og) {
    int idx = blockIdx.x * 256 + threadIdx.x;
    int n = idx >> 9;
    int rem = idx & 511;
    int e = rem >> 5;
    int d4 = (rem & 31) << 2;
    float wgt = rw[(size_t)n * 16 + e];
    const f32x4 o4 = *(const f32x4*)(ob + (size_t)n * Dd + d4);
    u16x4 st = {f2bf(wgt * o4[0]), f2bf(wgt * o4[1]), f2bf(wgt * o4[2]), f2bf(wgt * o4[3])};
    *(u16x4*)(og + (size_t)n * (Ee * Dd) + e * Dd + d4) = st;
}

extern "C" void kernel_launch(void* const* d_in, const int* in_sizes, int n_in,
                              void* d_out, int out_size, void* d_ws, size_t ws_size,
                              hipStream_t stream) {
    (void)in_sizes; (void)n_in; (void)out_size; (void)ws_size;
    const float* hidden = (const float*)d_in[0];
    const float* sim = (const float*)d_in[1];
    const float* gates = (const float*)d_in[2];
    const float* qp = (const float*)d_in[3];
    const float* kp = (const float*)d_in[4];
    const float* vp = (const float*)d_in[5];
    const float* op = (const float*)d_in[6];
    const int* minex = (const int*)d_in[7];
    float* out = (float*)d_out;

    char* w = (char*)d_ws;
    size_t off = 0;
    auto alloc = [&](size_t bytes) -> char* {
        char* p = w + off;
        off = (off + bytes + 255) & ~(size_t)255;
        return p;
    };
    unsigned short* xb = (unsigned short*)alloc((size_t)Nn * Cch * 2);
    unsigned short* wqkvT = (unsigned short*)alloc((size_t)Ee * 384 * Cch * 2);
    unsigned short* woT = (unsigned short*)alloc((size_t)Cch * Ee * Dd * 2);
    float* rw = (float*)alloc((size_t)Nn * Ee * 4);
    float* sninv = (float*)alloc(256);
    float* simT = (float*)alloc((size_t)Ee * Cch * 4);
    int* cnt = (int*)alloc(64 * 4);
    int* idx = (int*)alloc((size_t)Ee * CAP * 4);
    int* pos = (int*)alloc((size_t)Nn * 16 * 4);
    char* big = alloc((size_t)Bsz * Tt * Tt * 4);  // Pc / scores / og share this
    unsigned short* qb = (unsigned short*)alloc((size_t)Nn * Dd * 2);
    unsigned short* kb = (unsigned short*)alloc((size_t)Nn * Dd * 2);
    unsigned short* vb = (unsigned short*)alloc((size_t)Nn * Dd * 2);
    unsigned short* vT = (unsigned short*)alloc((size_t)Bsz * Dd * Tt * 2);
    float* ob = (float*)alloc((size_t)Nn * Dd * 4);
    unsigned short* Pc = (unsigned short*)big;
    float* scores = (float*)big;
    unsigned short* og = (unsigned short*)big;

    const float scale = 0.08838834764831845f;  // 1/sqrt(128)

    colnorm_kernel<<<1, 256, 0, stream>>>(sim, sninv, cnt);
    simt_kernel<<<(Ee * Cch) / 256, 256, 0, stream>>>(sim, simT);
    gating2_kernel<<<Nn / 4, 256, 0, stream>>>(hidden, simT, gates, sninv, minex, rw, xb, cnt, idx, pos);
    hipMemsetAsync(ob, 0, (size_t)Nn * Dd * 4, stream);

    // weight transposes (f32 -> bf16) into fused [E][384][C]
    transpose_f32_bf16<<<dim3(Dd / 32, Cch / 32, Ee), 256, 0, stream>>>(
        qp, wqkvT + 0 * Dd * Cch, Cch, Dd, (long)Cch * Dd, (long)384 * Cch);
    transpose_f32_bf16<<<dim3(Dd / 32, Cch / 32, Ee), 256, 0, stream>>>(
        kp, wqkvT + 1 * Dd * Cch, Cch, Dd, (long)Cch * Dd, (long)384 * Cch);
    transpose_f32_bf16<<<dim3(Dd / 32, Cch / 32, Ee), 256, 0, stream>>>(
        vp, wqkvT + 2 * Dd * Cch, Cch, Dd, (long)Cch * Dd, (long)384 * Cch);
    transpose_f32_bf16<<<dim3((Ee * Dd) / 32, Cch / 32, 1), 256, 0, stream>>>(
        op, woT, Ee * Dd, Cch, 0L, 0L);

    // gathered per-expert QKV projection, then combine
    gemm_qkv_gather<<<dim3(CAP / 128, 3, Ee), 256, 0, stream>>>(xb, wqkvT, idx, cnt, Pc);
    combine_qkv<<<(Nn * 32) / 256, 256, 0, stream>>>(Pc, rw, pos, qb, kb, vb);

    // V transpose per batch
    transpose_u16<<<dim3(Dd / 32, Tt / 32, Bsz), 256, 0, stream>>>(
        vb, vT, Tt, Dd, (long)Tt * Dd, (long)Dd * Tt);

    // scores = Q K^T * scale (causal)
    gemm_nt<1><<<dim3(Tt / 128, Tt / 128, Bsz), 256, 0, stream>>>(
        qb, (long)Tt * Dd, Dd, kb, (long)Tt * Dd, Dd, scores, (long)Tt * Tt, Tt, Dd, scale);
    softmax_kernel<<<dim3(Tt, Bsz), 256, 0, stream>>>(scores);
    // O = P V  — split-K over causal-active 512-chunks, atomic accumulate
    gemm_pv<<<dim3(Tt / 128, Tt / 512, Bsz), 256, 0, stream>>>(
        (const unsigned short*)scores, vT, ob);

    // og = rw-scaled o expanded over experts; single dense output GEMM
    og_kernel<<<(Nn * Ee * Dd / 4) / 256, 256, 0, stream>>>(ob, rw, og);
    gemm_nt<0><<<dim3(Nn / 128, Cch / 128, 1), 256, 0, stream>>>(
        og, 0L, Ee * Dd, woT, 0L, Ee * Dd, out, 0L, Cch, Ee * Dd, 1.0f);
}

// Round 4
// 506.863 us; speedup vs baseline: 1.4122x; 1.2406x over previous
//
#include <hip/hip_runtime.h>
#include <hip/hip_bf16.h>

#define DEV __device__ __forceinline__

typedef short bf16x8 __attribute__((ext_vector_type(8)));
typedef float f32x4 __attribute__((ext_vector_type(4)));
typedef unsigned short u16x4 __attribute__((ext_vector_type(4)));

static constexpr int Bsz = 4, Tt = 2048, Cch = 2048, Dd = 128, Ee = 16;
static constexpr int Nn = Bsz * Tt;
static constexpr int CAP = 4096;  // per-expert token capacity (mean ~1024)

DEV unsigned short f2bf(float v) {
    __hip_bfloat16 h = __float2bfloat16(v);
    return __builtin_bit_cast(unsigned short, h);
}
DEV float bf2f(unsigned short u) {
    unsigned int x = ((unsigned int)u) << 16;
    return __builtin_bit_cast(float, x);
}

// ---------------- sim_matrix column norms ----------------
__global__ __launch_bounds__(256) void colnorm_kernel(const float* __restrict__ sim,
                                                      float* __restrict__ sninv) {
    int e = threadIdx.x & 15, j = threadIdx.x >> 4;
    float ss = 0.f;
    for (int r = j; r < Cch; r += 16) {
        float v = sim[r * Ee + e];
        ss += v * v;
    }
    __shared__ float red[16][17];
    red[j][e] = ss;
    __syncthreads();
    if (threadIdx.x < 16) {
        float s = 0.f;
        for (int t = 0; t < 16; t++) s += red[t][threadIdx.x];
        sninv[threadIdx.x] = 1.f / fmaxf(sqrtf(s), 1e-12f);
    }
}

// ---------------- sim transpose: simT[e][c] = sim[c][e] ----------------
__global__ __launch_bounds__(256) void simt_kernel(const float* __restrict__ sim,
                                                   float* __restrict__ simT) {
    int i = blockIdx.x * 256 + threadIdx.x;  // 16*2048
    int e = i >> 11, c = i & 2047;
    simT[i] = sim[c * 16 + e];
}

// ---------------- gating: 1 wave per token, NO atomics; writes rw + onmask ----------------
__global__ __launch_bounds__(256) void gating2_kernel(
    const float* __restrict__ x, const float* __restrict__ simT,
    const float* __restrict__ gates, const float* __restrict__ sninv,
    const int* __restrict__ minex,
    float* __restrict__ rw, unsigned short* __restrict__ xb,
    int* __restrict__ onmaskv) {
    const int wave = threadIdx.x >> 6, lane = threadIdx.x & 63;
    const int n = blockIdx.x * 4 + wave;
    const f32x4* xr = (const f32x4*)(x + (size_t)n * Cch);
    const f32x4* st = (const f32x4*)simT;
    u16x4* xbr = (u16x4*)(xb + (size_t)n * Cch);
    float ss = 0.f;
    float d[16];
#pragma unroll
    for (int e = 0; e < 16; e++) d[e] = 0.f;
#pragma unroll
    for (int it = 0; it < 8; it++) {
        int i = it * 64 + lane;
        f32x4 xv = xr[i];
        ss += xv[0] * xv[0] + xv[1] * xv[1] + xv[2] * xv[2] + xv[3] * xv[3];
        u16x4 xc = {f2bf(xv[0]), f2bf(xv[1]), f2bf(xv[2]), f2bf(xv[3])};
        xbr[i] = xc;
#pragma unroll
        for (int e = 0; e < 16; e++) {
            f32x4 sv = st[e * 512 + i];
            d[e] += xv[0] * sv[0] + xv[1] * sv[1] + xv[2] * sv[2] + xv[3] * sv[3];
        }
    }
#pragma unroll
    for (int off = 32; off; off >>= 1) {
        ss += __shfl_down(ss, off);
#pragma unroll
        for (int e = 0; e < 16; e++) d[e] += __shfl_down(d[e], off);
    }
    if (lane == 0) {
        float inv = 1.f / fmaxf(sqrtf(ss), 1e-12f);
        float logit[16];
        int onmask = 0;
#pragma unroll
        for (int e = 0; e < 16; e++) {
            float sg = 1.f / (1.f + __expf(-gates[e]));
            float l = d[e] * inv * sninv[e] - sg;
            logit[e] = l;
            if (l > 0.f) onmask |= (1 << e);
        }
        if (onmask == 0) {
            int k = *minex;
            int ch = 0;
            for (int kk = 0; kk < k; kk++) {
                float bv = -1e30f;
                int be = 0;
#pragma unroll
                for (int e = 0; e < 16; e++)
                    if (!((ch >> e) & 1) && logit[e] > bv) { bv = logit[e]; be = e; }
                ch |= (1 << be);
            }
            onmask = ch;
        }
        float mx = -1e30f;
#pragma unroll
        for (int e = 0; e < 16; e++)
            if ((onmask >> e) & 1) mx = fmaxf(mx, fmaxf(logit[e], 0.f));
        float pe[16];
        float sum = 0.f;
#pragma unroll
        for (int e = 0; e < 16; e++) {
            pe[e] = ((onmask >> e) & 1) ? __expf(fmaxf(logit[e], 0.f) - mx) : 0.f;
            sum += pe[e];
        }
        float isum = 1.f / sum;
#pragma unroll
        for (int e = 0; e < 16; e++) rw[(size_t)n * 16 + e] = pe[e] * isum;
        onmaskv[n] = onmask;
    }
}

// ---------------- deterministic expert-list scan (replaces atomics) ----------------
// one block per expert; 256 threads x 32 tokens each; prefix-sum slot assignment
__global__ __launch_bounds__(256) void scan_kernel(
    const int* __restrict__ onmaskv,
    int* __restrict__ idx, int* __restrict__ pos, int* __restrict__ cnt) {
    const int e = blockIdx.x;
    const int tid = threadIdx.x;
    const int base = tid * 32;
    int om[32];
    int c = 0;
#pragma unroll
    for (int i = 0; i < 32; i++) {
        om[i] = (onmaskv[base + i] >> e) & 1;
        c += om[i];
    }
    // inclusive wave scan of c
    const int lane = tid & 63, w = tid >> 6;
    int sc = c;
#pragma unroll
    for (int off = 1; off < 64; off <<= 1) {
        int t = __shfl_up(sc, off);
        if (lane >= off) sc += t;
    }
    __shared__ int wsum[4];
    if (lane == 63) wsum[w] = sc;
    __syncthreads();
    int wbase = 0;
    for (int i = 0; i < w; i++) wbase += wsum[i];
    int slot = wbase + sc - c;  // exclusive prefix
#pragma unroll
    for (int i = 0; i < 32; i++) {
        int n = base + i;
        int p = -1;
        if (om[i]) {
            if (slot < CAP) {
                idx[(size_t)e * CAP + slot] = n;
                p = slot;
            }
            slot++;
        }
        pos[(size_t)n * 16 + e] = p;
    }
    if (tid == 255) cnt[e] = slot;
}

// ---------------- transposes ----------------
__global__ __launch_bounds__(256) void transpose_f32_bf16(
    const float* __restrict__ src, unsigned short* __restrict__ dst,
    int R, int Ccol, long ss, long ds) {
    __shared__ float tile[32][33];
    src += (size_t)blockIdx.z * ss;
    dst += (size_t)blockIdx.z * ds;
    int bx = blockIdx.x * 32, by = blockIdx.y * 32;
    int tx = threadIdx.x & 31, ty = threadIdx.x >> 5;
#pragma unroll
    for (int i = 0; i < 4; i++)
        tile[ty + i * 8][tx] = src[(size_t)(by + ty + i * 8) * Ccol + bx + tx];
    __syncthreads();
#pragma unroll
    for (int i = 0; i < 4; i++)
        dst[(size_t)(bx + ty + i * 8) * R + by + tx] = f2bf(tile[tx][ty + i * 8]);
}

__global__ __launch_bounds__(256) void transpose_u16(
    const unsigned short* __restrict__ src, unsigned short* __restrict__ dst,
    int R, int Ccol, long ss, long ds) {
    __shared__ unsigned short tile[32][33];
    src += (size_t)blockIdx.z * ss;
    dst += (size_t)blockIdx.z * ds;
    int bx = blockIdx.x * 32, by = blockIdx.y * 32;
    int tx = threadIdx.x & 31, ty = threadIdx.x >> 5;
#pragma unroll
    for (int i = 0; i < 4; i++)
        tile[ty + i * 8][tx] = src[(size_t)(by + ty + i * 8) * Ccol + bx + tx];
    __syncthreads();
#pragma unroll
    for (int i = 0; i < 4; i++)
        dst[(size_t)(bx + ty + i * 8) * R + by + tx] = tile[tx][ty + i * 8];
}

// ---------------- NT GEMM: Out[M,N] = A[M,K] * BT[N,K]^T (bf16 in, f32 out) ----------------
template <int CAUSAL>
__global__ __launch_bounds__(256) void gemm_nt(
    const unsigned short* __restrict__ A, long strideA, int lda,
    const unsigned short* __restrict__ BT, long strideB, int ldb,
    float* __restrict__ Out, long strideO, int ldo,
    int K, float scale) {
    __shared__ alignas(16) unsigned short As[128 * 64];
    __shared__ alignas(16) unsigned short Bs[128 * 64];
    const int bm = blockIdx.x * 128;
    const int bn = blockIdx.y * 128;
    if (CAUSAL && bn > bm + 127) return;
    A += (size_t)blockIdx.z * strideA;
    BT += (size_t)blockIdx.z * strideB;
    Out += (size_t)blockIdx.z * strideO;
    const int tid = threadIdx.x;
    const int wave = tid >> 6, lane = tid & 63;
    const int lr = lane & 15, lg = lane >> 4;
    const int wr = (wave >> 1) * 64, wc = (wave & 1) * 64;
    f32x4 acc[4][4] = {};

    for (int k0 = 0; k0 < K; k0 += 64) {
        __syncthreads();
#pragma unroll
        for (int i = 0; i < 4; i++) {
            int t = i * 256 + tid;
            int row = t >> 3;
            int kc = (t & 7) << 3;
            __builtin_amdgcn_global_load_lds(
                (const __attribute__((address_space(1))) void*)(A + (size_t)(bm + row) * lda + k0 + kc),
                (__attribute__((address_space(3))) void*)(As + (i * 4 + wave) * 512),
                16, 0, 0);
        }
#pragma unroll
        for (int i = 0; i < 4; i++) {
            int t = i * 256 + tid;
            int row = t >> 3;
            int kc = (t & 7) << 3;
            __builtin_amdgcn_global_load_lds(
                (const __attribute__((address_space(1))) void*)(BT + (size_t)(bn + row) * ldb + k0 + kc),
                (__attribute__((address_space(3))) void*)(Bs + (i * 4 + wave) * 512),
                16, 0, 0);
        }
        __syncthreads();
#pragma unroll
        for (int kk = 0; kk < 2; kk++) {
            bf16x8 a[4], b[4];
#pragma unroll
            for (int m = 0; m < 4; m++)
                a[m] = *(const bf16x8*)(As + (wr + m * 16 + lr) * 64 + kk * 32 + lg * 8);
#pragma unroll
            for (int n = 0; n < 4; n++)
                b[n] = *(const bf16x8*)(Bs + (wc + n * 16 + lr) * 64 + kk * 32 + lg * 8);
#pragma unroll
            for (int m = 0; m < 4; m++)
#pragma unroll
                for (int n = 0; n < 4; n++)
                    acc[m][n] = __builtin_amdgcn_mfma_f32_16x16x32_bf16(a[m], b[n], acc[m][n], 0, 0, 0);
        }
    }
#pragma unroll
    for (int m = 0; m < 4; m++) {
#pragma unroll
        for (int n = 0; n < 4; n++) {
#pragma unroll
            for (int r = 0; r < 4; r++) {
                int grow = bm + wr + m * 16 + lg * 4 + r;
                int gcol = bn + wc + n * 16 + lr;
                if (!CAUSAL || gcol <= grow)
                    Out[(size_t)grow * ldo + gcol] = acc[m][n][r] * scale;
            }
        }
    }
}

// ---------------- PV GEMM: split-K over causal-active chunks, atomic f32 accumulate ----------------
__global__ __launch_bounds__(256) void gemm_pv(
    const unsigned short* __restrict__ P, const unsigned short* __restrict__ vT,
    float* __restrict__ ob) {
    const int bm = blockIdx.x * 128;
    const int kb = blockIdx.y * 512;
    if (kb > bm + 127) return;
    const unsigned short* Pb = P + (size_t)blockIdx.z * Tt * 4096;
    const unsigned short* Vb = vT + (size_t)blockIdx.z * Dd * Tt;
    float* Ob = ob + (size_t)blockIdx.z * Tt * Dd;
    __shared__ alignas(16) unsigned short As[128 * 64];
    __shared__ alignas(16) unsigned short Bs[128 * 64];
    const int tid = threadIdx.x;
    const int wave = tid >> 6, lane = tid & 63;
    const int lr = lane & 15, lg = lane >> 4;
    const int wr = (wave >> 1) * 64, wc = (wave & 1) * 64;
    f32x4 acc[4][4] = {};

    for (int k0 = kb; k0 < kb + 512; k0 += 64) {
        __syncthreads();
#pragma unroll
        for (int i = 0; i < 4; i++) {
            int t = i * 256 + tid;
            int row = t >> 3;
            int kc = (t & 7) << 3;
            __builtin_amdgcn_global_load_lds(
                (const __attribute__((address_space(1))) void*)(Pb + (size_t)(bm + row) * 4096 + k0 + kc),
                (__attribute__((address_space(3))) void*)(As + (i * 4 + wave) * 512),
                16, 0, 0);
        }
#pragma unroll
        for (int i = 0; i < 4; i++) {
            int t = i * 256 + tid;
            int row = t >> 3;
            int kc = (t & 7) << 3;
            __builtin_amdgcn_global_load_lds(
                (const __attribute__((address_space(1))) void*)(Vb + (size_t)row * Tt + k0 + kc),
                (__attribute__((address_space(3))) void*)(Bs + (i * 4 + wave) * 512),
                16, 0, 0);
        }
        __syncthreads();
#pragma unroll
        for (int kk = 0; kk < 2; kk++) {
            bf16x8 a[4], b[4];
#pragma unroll
            for (int m = 0; m < 4; m++)
                a[m] = *(const bf16x8*)(As + (wr + m * 16 + lr) * 64 + kk * 32 + lg * 8);
#pragma unroll
            for (int n = 0; n < 4; n++)
                b[n] = *(const bf16x8*)(Bs + (wc + n * 16 + lr) * 64 + kk * 32 + lg * 8);
#pragma unroll
            for (int m = 0; m < 4; m++)
#pragma unroll
                for (int n = 0; n < 4; n++)
                    acc[m][n] = __builtin_amdgcn_mfma_f32_16x16x32_bf16(a[m], b[n], acc[m][n], 0, 0, 0);
        }
    }
#pragma unroll
    for (int m = 0; m < 4; m++)
#pragma unroll
        for (int n = 0; n < 4; n++)
#pragma unroll
            for (int r = 0; r < 4; r++) {
                int grow = bm + wr + m * 16 + lg * 4 + r;
                int gcol = wc + n * 16 + lr;
                atomicAdd(&Ob[(size_t)grow * Dd + gcol], acc[m][n][r]);
            }
}

// ---------------- gathered QKV projection ----------------
__global__ __launch_bounds__(256) void gemm_qkv_gather(
    const unsigned short* __restrict__ X, const unsigned short* __restrict__ W,
    const int* __restrict__ idx, const int* __restrict__ cnt,
    unsigned short* __restrict__ P) {
    const int e = blockIdx.z;
    const int cn = min(cnt[e], CAP);
    const int bm = blockIdx.x * 128;
    if (bm >= cn) return;
    const int bn = blockIdx.y * 128;
    __shared__ alignas(16) unsigned short As[128 * 64];
    __shared__ alignas(16) unsigned short Bs[128 * 64];
    __shared__ int toks[128];
    const int tid = threadIdx.x;
    if (tid < 128) toks[tid] = idx[(size_t)e * CAP + min(bm + tid, cn - 1)];
    const unsigned short* Wb = W + ((size_t)e * 384 + bn) * Cch;
    const int wave = tid >> 6, lane = tid & 63;
    const int lr = lane & 15, lg = lane >> 4;
    const int wr = (wave >> 1) * 64, wc = (wave & 1) * 64;
    f32x4 acc[4][4] = {};

    for (int k0 = 0; k0 < Cch; k0 += 64) {
        __syncthreads();
#pragma unroll
        for (int i = 0; i < 4; i++) {
            int t = i * 256 + tid;
            int row = t >> 3;
            int kc = (t & 7) << 3;
            __builtin_amdgcn_global_load_lds(
                (const __attribute__((address_space(1))) void*)(X + (size_t)toks[row] * Cch + k0 + kc),
                (__attribute__((address_space(3))) void*)(As + (i * 4 + wave) * 512),
                16, 0, 0);
        }
#pragma unroll
        for (int i = 0; i < 4; i++) {
            int t = i * 256 + tid;
            int row = t >> 3;
            int kc = (t & 7) << 3;
            __builtin_amdgcn_global_load_lds(
                (const __attribute__((address_space(1))) void*)(Wb + (size_t)row * Cch + k0 + kc),
                (__attribute__((address_space(3))) void*)(Bs + (i * 4 + wave) * 512),
                16, 0, 0);
        }
        __syncthreads();
#pragma unroll
        for (int kk = 0; kk < 2; kk++) {
            bf16x8 a[4], b[4];
#pragma unroll
            for (int m = 0; m < 4; m++)
                a[m] = *(const bf16x8*)(As + (wr + m * 16 + lr) * 64 + kk * 32 + lg * 8);
#pragma unroll
            for (int n = 0; n < 4; n++)
                b[n] = *(const bf16x8*)(Bs + (wc + n * 16 + lr) * 64 + kk * 32 + lg * 8);
#pragma unroll
            for (int m = 0; m < 4; m++)
#pragma unroll
                for (int n = 0; n < 4; n++)
                    acc[m][n] = __builtin_amdgcn_mfma_f32_16x16x32_bf16(a[m], b[n], acc[m][n], 0, 0, 0);
        }
    }
#pragma unroll
    for (int m = 0; m < 4; m++)
#pragma unroll
        for (int n = 0; n < 4; n++)
#pragma unroll
            for (int r = 0; r < 4; r++) {
                int slot = bm + wr + m * 16 + lg * 4 + r;
                int col = bn + wc + n * 16 + lr;
                if (slot < cn)
                    P[((size_t)e * CAP + slot) * 384 + col] = f2bf(acc[m][n][r]);
            }
}

// ---------------- combine q/k/v ----------------
__global__ __launch_bounds__(256) void combine_qkv(
    const unsigned short* __restrict__ P, const float* __restrict__ rw,
    const int* __restrict__ pos,
    unsigned short* __restrict__ qb, unsigned short* __restrict__ kb,
    unsigned short* __restrict__ vb) {
    int i = blockIdx.x * 256 + threadIdx.x;
    int n = i >> 5;
    int d4 = (i & 31) << 2;
    float aq[4] = {}, ak[4] = {}, av[4] = {};
#pragma unroll
    for (int e = 0; e < 16; e++) {
        int p = pos[(size_t)n * 16 + e];
        if (p >= 0) {
            float w = rw[(size_t)n * 16 + e];
            const unsigned short* row = P + ((size_t)e * CAP + p) * 384 + d4;
            const u16x4 q4 = *(const u16x4*)(row);
            const u16x4 k4 = *(const u16x4*)(row + 128);
            const u16x4 v4 = *(const u16x4*)(row + 256);
#pragma unroll
            for (int j = 0; j < 4; j++) {
                aq[j] += w * bf2f(q4[j]);
                ak[j] += w * bf2f(k4[j]);
                av[j] += w * bf2f(v4[j]);
            }
        }
    }
    u16x4 sq = {f2bf(aq[0]), f2bf(aq[1]), f2bf(aq[2]), f2bf(aq[3])};
    u16x4 sk = {f2bf(ak[0]), f2bf(ak[1]), f2bf(ak[2]), f2bf(ak[3])};
    u16x4 sv = {f2bf(av[0]), f2bf(av[1]), f2bf(av[2]), f2bf(av[3])};
    *(u16x4*)(qb + (size_t)n * Dd + d4) = sq;
    *(u16x4*)(kb + (size_t)n * Dd + d4) = sk;
    *(u16x4*)(vb + (size_t)n * Dd + d4) = sv;
}

// ---------------- causal row softmax, in-place f32 -> bf16 ----------------
__global__ __launch_bounds__(256) void softmax_kernel(float* __restrict__ scores) {
    int i = blockIdx.x, b = blockIdx.y;
    float* row = scores + ((size_t)b * Tt + i) * Tt;
    int nv = i + 1;
    float v[8];
    int cnt = 0;
    float mx = -1e30f;
    for (int j = threadIdx.x; j < nv; j += 256) {
        float t = row[j];
        v[cnt++] = t;
        mx = fmaxf(mx, t);
    }
    __shared__ float sred[4];
    int w = threadIdx.x >> 6;
#pragma unroll
    for (int off = 32; off; off >>= 1) mx = fmaxf(mx, __shfl_down(mx, off));
    if ((threadIdx.x & 63) == 0) sred[w] = mx;
    __syncthreads();
    float m = fmaxf(fmaxf(sred[0], sred[1]), fmaxf(sred[2], sred[3]));
    float s = 0.f;
    for (int t = 0; t < cnt; t++) {
        v[t] = __expf(v[t] - m);
        s += v[t];
    }
    __syncthreads();
#pragma unroll
    for (int off = 32; off; off >>= 1) s += __shfl_down(s, off);
    if ((threadIdx.x & 63) == 0) sred[w] = s;
    __syncthreads();
    float inv = 1.f / (sred[0] + sred[1] + sred[2] + sred[3]);
    unsigned short* prow = (unsigned short*)row;
    cnt = 0;
    for (int j = threadIdx.x; j < Tt; j += 256) {
        float pv = 0.f;
        if (j < nv) pv = v[cnt++] * inv;
        prow[j] = f2bf(pv);
    }
}

// ---------------- og[n, e*D+d] = rw[n,e] * o[n,d] ----------------
__global__ __launch_bounds__(256) void og_kernel(
    const float* __restrict__ ob, const float* __restrict__ rw,
    unsigned short* __restrict__ og) {
    int idx = blockIdx.x * 256 + threadIdx.x;
    int n = idx >> 9;
    int rem = idx & 511;
    int e = rem >> 5;
    int d4 = (rem & 31) << 2;
    float wgt = rw[(size_t)n * 16 + e];
    const f32x4 o4 = *(const f32x4*)(ob + (size_t)n * Dd + d4);
    u16x4 st = {f2bf(wgt * o4[0]), f2bf(wgt * o4[1]), f2bf(wgt * o4[2]), f2bf(wgt * o4[3])};
    *(u16x4*)(og + (size_t)n * (Ee * Dd) + e * Dd + d4) = st;
}

extern "C" void kernel_launch(void* const* d_in, const int* in_sizes, int n_in,
                              void* d_out, int out_size, void* d_ws, size_t ws_size,
                              hipStream_t stream) {
    (void)in_sizes; (void)n_in; (void)out_size; (void)ws_size;
    const float* hidden = (const float*)d_in[0];
    const float* sim = (const float*)d_in[1];
    const float* gates = (const float*)d_in[2];
    const float* qp = (const float*)d_in[3];
    const float* kp = (const float*)d_in[4];
    const float* vp = (const float*)d_in[5];
    const float* op = (const float*)d_in[6];
    const int* minex = (const int*)d_in[7];
    float* out = (float*)d_out;

    char* w = (char*)d_ws;
    size_t off = 0;
    auto alloc = [&](size_t bytes) -> char* {
        char* p = w + off;
        off = (off + bytes + 255) & ~(size_t)255;
        return p;
    };
    unsigned short* xb = (unsigned short*)alloc((size_t)Nn * Cch * 2);
    unsigned short* wqkvT = (unsigned short*)alloc((size_t)Ee * 384 * Cch * 2);
    unsigned short* woT = (unsigned short*)alloc((size_t)Cch * Ee * Dd * 2);
    float* rw = (float*)alloc((size_t)Nn * Ee * 4);
    float* sninv = (float*)alloc(256);
    float* simT = (float*)alloc((size_t)Ee * Cch * 4);
    int* cnt = (int*)alloc(64 * 4);
    int* onmaskv = (int*)alloc((size_t)Nn * 4);
    int* idx = (int*)alloc((size_t)Ee * CAP * 4);
    int* pos = (int*)alloc((size_t)Nn * 16 * 4);
    char* big = alloc((size_t)Bsz * Tt * Tt * 4);  // Pc / scores / og share this
    unsigned short* qb = (unsigned short*)alloc((size_t)Nn * Dd * 2);
    unsigned short* kb = (unsigned short*)alloc((size_t)Nn * Dd * 2);
    unsigned short* vb = (unsigned short*)alloc((size_t)Nn * Dd * 2);
    unsigned short* vT = (unsigned short*)alloc((size_t)Bsz * Dd * Tt * 2);
    float* ob = (float*)alloc((size_t)Nn * Dd * 4);
    unsigned short* Pc = (unsigned short*)big;
    float* scores = (float*)big;
    unsigned short* og = (unsigned short*)big;

    const float scale = 0.08838834764831845f;  // 1/sqrt(128)

    colnorm_kernel<<<1, 256, 0, stream>>>(sim, sninv);
    simt_kernel<<<(Ee * Cch) / 256, 256, 0, stream>>>(sim, simT);
    gating2_kernel<<<Nn / 4, 256, 0, stream>>>(hidden, simT, gates, sninv, minex, rw, xb, onmaskv);
    scan_kernel<<<Ee, 256, 0, stream>>>(onmaskv, idx, pos, cnt);
    hipMemsetAsync(ob, 0, (size_t)Nn * Dd * 4, stream);

    // weight transposes (f32 -> bf16) into fused [E][384][C]
    transpose_f32_bf16<<<dim3(Dd / 32, Cch / 32, Ee), 256, 0, stream>>>(
        qp, wqkvT + 0 * Dd * Cch, Cch, Dd, (long)Cch * Dd, (long)384 * Cch);
    transpose_f32_bf16<<<dim3(Dd / 32, Cch / 32, Ee), 256, 0, stream>>>(
        kp, wqkvT + 1 * Dd * Cch, Cch, Dd, (long)Cch * Dd, (long)384 * Cch);
    transpose_f32_bf16<<<dim3(Dd / 32, Cch / 32, Ee), 256, 0, stream>>>(
        vp, wqkvT + 2 * Dd * Cch, Cch, Dd, (long)Cch * Dd, (long)384 * Cch);
    transpose_f32_bf16<<<dim3((Ee * Dd) / 32, Cch / 32, 1), 256, 0, stream>>>(
        op, woT, Ee * Dd, Cch, 0L, 0L);

    // gathered per-expert QKV projection, then combine
    gemm_qkv_gather<<<dim3(CAP / 128, 3, Ee), 256, 0, stream>>>(xb, wqkvT, idx, cnt, Pc);
    combine_qkv<<<(Nn * 32) / 256, 256, 0, stream>>>(Pc, rw, pos, qb, kb, vb);

    // V transpose per batch
    transpose_u16<<<dim3(Dd / 32, Tt / 32, Bsz), 256, 0, stream>>>(
        vb, vT, Tt, Dd, (long)Tt * Dd, (long)Dd * Tt);

    // scores = Q K^T * scale (causal)
    gemm_nt<1><<<dim3(Tt / 128, Tt / 128, Bsz), 256, 0, stream>>>(
        qb, (long)Tt * Dd, Dd, kb, (long)Tt * Dd, Dd, scores, (long)Tt * Tt, Tt, Dd, scale);
    softmax_kernel<<<dim3(Tt, Bsz), 256, 0, stream>>>(scores);
    // O = P V  — split-K over causal-active 512-chunks, atomic accumulate
    gemm_pv<<<dim3(Tt / 128, Tt / 512, Bsz), 256, 0, stream>>>(
        (const unsigned short*)scores, vT, ob);

    // og = rw-scaled o expanded over experts; single dense output GEMM
    og_kernel<<<(Nn * Ee * Dd / 4) / 256, 256, 0, stream>>>(ob, rw, og);
    gemm_nt<0><<<dim3(Nn / 128, Cch / 128, 1), 256, 0, stream>>>(
        og, 0L, Ee * Dd, woT, 0L, Ee * Dd, out, 0L, Cch, Ee * Dd, 1.0f);
}